// Round 5
// baseline (400.793 us; speedup 1.0000x reference)
//
#include <hip/hip_runtime.h>
#include <hip/hip_bf16.h>

#define T_LEN 524288
#define NTAG 64
#define START_TAG 62
#define STOP_TAG 63
#define NEGV -10000.0f

// speculative-chunk decomposition, wave-synchronous engine.
// R5: tr row truly arch-VGPR-resident. R3/R4 failed because the 128-VGPR cap
// (launch_bounds(256,4)) made the allocator remat/AGPR-shuttle the 64-reg tr
// array (VGPR_Count=64 both rounds, ~+100 VALU/step). Fix = budget: 2
// waves/SIMD (256-VGPR cap) + geometry KCH=2048/CL=256 so grid=512 blocks is
// exactly 2 blocks/CU -> one full residency round, and warmup overhead drops
// (64/320 vs 64/192 of steps).
#define KCH 2048         // chunks (= waves)
#define CL  256          // trusted steps per chunk
#define WU  64           // warmup steps (decision collapse; score drift checked)
#define WPB 4            // waves (chunks) per block

#define SG  64           // chunks per supergroup
#define NSG (KCH / SG)   // 32

typedef float v2f __attribute__((ext_vector_type(2)));

// trL: stride 65 floats -> per-lane scalar reads at bank (lane+c)%32 = 2-way (free).
// fv: per-wave ping-pong, 16B aligned for b128 broadcast reads.
struct BlockLDS {
    float trL[NTAG * 65];                   // 16640 B, shared by 4 waves
    __align__(16) float fv[WPB][2][NTAG];   // 2048 B
};

static __device__ __forceinline__ float max3f(float a, float b, float c) {
    return fmaxf(fmaxf(a, b), c);      // clang fuses to v_max3_f32
}
static __device__ __forceinline__ v2f mk2(float a, float b) {
    v2f r; r.x = a; r.y = b; return r;
}

union Q4 { float4 q; v2f h[2]; };

// Wave-synchronous max-plus engine, register-tr tournament edition.
// Phase A: fv broadcast (uniform ds_read_b128) + tr in VGPRs -> 32 packed
// adds + max3 tree -> gm[8], global max t.
// Phase B (MODE 1): argmax by exact fp equality (fmax returns an input
// bit-exactly; adds recomputed with identical IEEE adds). First-match scan
// = jnp.argmax first-occurrence semantics. fv group via per-lane b128,
// tr group via stride-65 trL scalar reads (runtime g -> LDS, 2-way banks).
template<int MODE>
__device__ __forceinline__ void wave_run(
    int t0, int nsteps, const float* __restrict__ feats,
    const float* __restrict__ trans,
    unsigned int* __restrict__ bpg, float (*fv)[NTAG],
    const float* __restrict__ trL, int lane)
{
    // ---- transition row in registers, pinned against remat ----
    v2f tr[32];
    {
        const float4* t4 = (const float4*)(trans + (size_t)lane * NTAG);
#pragma unroll
        for (int j = 0; j < 16; ++j) {
            float4 v = t4[j];
            tr[2 * j + 0] = mk2(v.x, v.y);
            tr[2 * j + 1] = mk2(v.z, v.w);
        }
#pragma unroll
        for (int j = 0; j < 32; ++j)
            asm volatile("" : "+v"(tr[j]));
    }
    const float* trrow = &trL[lane * 65];
    const float* fp = feats + (size_t)t0 * NTAG + lane;
    float fA[4], fB[4];
#pragma unroll
    for (int i = 0; i < 4; ++i) fA[i] = fp[i * NTAG];
    fp += 4 * NTAG;
    unsigned int acc = 0;
    unsigned int* bp = bpg + ((size_t)t0 >> 2) * NTAG + lane;
#pragma unroll 1
    for (int tt = 0; tt < nsteps; tt += 4) {
        const bool hav = (tt + 4 < nsteps);
        if (hav) {
#pragma unroll
            for (int i = 0; i < 4; ++i) fB[i] = fp[i * NTAG];
            fp += 4 * NTAG;
        }
#pragma unroll
        for (int s = 0; s < 4; ++s) {
            const int st = tt + s;
            const float* fvp = fv[st & 1];
            float* fvn = fv[(st + 1) & 1];
            const Q4* fq = (const Q4*)fvp;

            // ---- phase A ----
            float gm[8];
#pragma unroll
            for (int g = 0; g < 8; ++g) {
                Q4 x0 = fq[2 * g + 0];             // uniform -> broadcast
                Q4 x1 = fq[2 * g + 1];
                v2f c01 = x0.h[0] + tr[4 * g + 0];
                v2f c23 = x0.h[1] + tr[4 * g + 1];
                v2f c45 = x1.h[0] + tr[4 * g + 2];
                v2f c67 = x1.h[1] + tr[4 * g + 3];
                const float m1 = max3f(c01.x, c01.y, c23.x);
                const float m2 = max3f(c23.y, c45.x, c45.y);
                const float m3 = max3f(c67.x, c67.y, m1);
                gm[g] = fmaxf(m2, m3);
            }
            const float ga = max3f(gm[0], gm[1], gm[2]);
            const float gb = max3f(gm[3], gm[4], gm[5]);
            const float gc = max3f(gm[6], gm[7], ga);
            const float t  = fmaxf(gb, gc);
            fvn[lane] = t + fA[s];

            if (MODE == 1) {
                // ---- phase B: exact-equality argmax recovery ----
                int g = 7;
                if (gm[6] == t) g = 6;
                if (gm[5] == t) g = 5;
                if (gm[4] == t) g = 4;
                if (gm[3] == t) g = 3;
                if (gm[2] == t) g = 2;
                if (gm[1] == t) g = 1;
                if (gm[0] == t) g = 0;
                const Q4* yq = (const Q4*)(fvp + (g << 3));  // 32B aligned
                Q4 y0 = yq[0];
                Q4 y1 = yq[1];
                const float* tb = trrow + (g << 3);
                const float e0 = y0.h[0].x + tb[0], e1 = y0.h[0].y + tb[1];
                const float e2 = y0.h[1].x + tb[2], e3 = y0.h[1].y + tb[3];
                const float e4 = y1.h[0].x + tb[4], e5 = y1.h[0].y + tb[5];
                const float e6 = y1.h[1].x + tb[6], e7 = y1.h[1].y + tb[7];
                int j = 7;
                if (e6 == t) j = 6;
                if (e5 == t) j = 5;
                if (e4 == t) j = 4;
                if (e3 == t) j = 3;
                if (e2 == t) j = 2;
                if (e1 == t) j = 1;
                if (e0 == t) j = 0;
                const int idx = (g << 3) | j;
                acc |= (unsigned int)idx << (8 * s);
                if (s == 3) {
                    *bp = acc;
                    bp += NTAG;
                    acc = 0;
                }
            }
        }
        if (hav) {
#pragma unroll
            for (int i = 0; i < 4; ++i) fA[i] = fB[i];
        }
    }
}

__device__ __forceinline__ void load_trans_lds(const float* __restrict__ trans,
                                               int lane, float* trL)
{
    const float4* trow = (const float4*)(trans + (size_t)lane * NTAG);
    float* dst = trL + lane * 65;
#pragma unroll
    for (int j = 0; j < 16; ++j) {
        float4 v = trow[j];
        dst[j * 4 + 0] = v.x; dst[j * 4 + 1] = v.y;
        dst[j * 4 + 2] = v.z; dst[j * 4 + 3] = v.w;
    }
}

// ---- pass1: warmup + trusted chunk + fused backtrack map (bpg re-read) ----
// launch_bounds(256, 2): 256-VGPR cap so tr[32] (64 regs) stays arch-resident.
// grid = 512 blocks = exactly 2 blocks/CU, one residency round.
__global__ __launch_bounds__(256, 2) void pass1_kernel(
    const float* __restrict__ feats, const float* __restrict__ trans,
    unsigned int* __restrict__ bpg, float* __restrict__ ovl,
    float* __restrict__ bnd, unsigned char* __restrict__ maps)
{
    __shared__ BlockLDS L;
    const int lane = threadIdx.x & 63;
    const int w = threadIdx.x >> 6;
    const int k = blockIdx.x * WPB + w;
    load_trans_lds(trans, lane, L.trL);   // each lane writes & reads its own row

    float (*fv)[NTAG] = L.fv[w];
    if (k == 0) {
        fv[0][lane] = (lane == START_TAG) ? 0.0f : NEGV;
    } else {
        fv[0][lane] = 0.0f;
    }
    if (k > 0) {
        wave_run<0>(k * CL - WU, WU, feats, trans, nullptr, fv, L.trL, lane); // WU even -> fv[0]
        ovl[(size_t)k * NTAG + lane] = fv[0][lane];
    }
    wave_run<1>(k * CL, CL, feats, trans, bpg, fv, L.trL, lane);
    bnd[(size_t)(k + 1) * NTAG + lane] = fv[0][lane];                  // CL even

    // fused backtrack: chase this chunk's bptr (descending t) -> block map.
    // Reads back the bpg words this lane just wrote (same address, L2-hot).
    asm volatile("s_waitcnt vmcnt(0)" ::: "memory");
    int cur = lane;
    const size_t base = ((size_t)(k * CL) >> 2) * NTAG + lane;
#pragma unroll 4
    for (int t4 = CL / 4 - 1; t4 >= 0; --t4) {
        unsigned int b4 = bpg[base + (size_t)t4 * NTAG];
#pragma unroll
        for (int j = 3; j >= 0; --j) {
            unsigned int u = __shfl(b4, cur);
            cur = (u >> (8 * j)) & 255;
        }
    }
    maps[(size_t)k * NTAG + lane] = (unsigned char)cur;
}

// ---- mid: compose (blocks 0..NSG-1) || finalize partial reduce (blocks NSG..NSG+63) ----
__global__ __launch_bounds__(1024) void mid_kernel(
    const unsigned char* __restrict__ maps, unsigned char* __restrict__ smaps,
    const float* __restrict__ bnd, const float* __restrict__ ovl,
    float* __restrict__ pc, float* __restrict__ pe, int* __restrict__ pb)
{
    __shared__ float sc[16], se[16];
    __shared__ int sb[16];
    if (blockIdx.x < NSG) {
        if (threadIdx.x < 64) {            // single-wave map composition
            const int lane = threadIdx.x, j = blockIdx.x;
            int cur = lane;
#pragma unroll 4
            for (int i = (j + 1) * SG - 1; i >= j * SG; --i) {
                int m = maps[(size_t)i * NTAG + lane];
                cur = __shfl(m, cur);
            }
            smaps[j * NTAG + lane] = (unsigned char)cur;
        }
        return;
    }
    const int tid = threadIdx.x, w = tid >> 6, lane = tid & 63;
    const int gw = (blockIdx.x - NSG) * 16 + w;    // 1024 warps total
    float csum = 0.f, esum = 0.f;
    int bad = 0;
    for (int k = 1 + gw; k < KCH; k += 1024) {
        float d = bnd[(size_t)k * NTAG + lane] - ovl[(size_t)k * NTAG + lane];
        float d0 = __shfl(d, 0);
        float sp = fabsf(d - d0);
#pragma unroll
        for (int o = 1; o < 64; o <<= 1) sp = fmaxf(sp, __shfl_xor(sp, o));
        csum += d0; esum += sp;
        if (!(fabsf(d0) < 1.0e7f)) bad = 1;        // incl. NaN
    }
    if (lane == 0) { sc[w] = csum; se[w] = esum; sb[w] = bad; }
    __syncthreads();
    if (tid == 0) {
        float c = 0.f, e = 0.f; int b = 0;
        for (int i = 0; i < 16; ++i) { c += sc[i]; e += se[i]; b |= sb[i]; }
        pc[blockIdx.x - NSG] = c; pe[blockIdx.x - NSG] = e; pb[blockIdx.x - NSG] = b;
    }
}

// ---- finalize: combine partials + terminal argmax + integrated fallback ----
__global__ __launch_bounds__(64) void finalize_final_kernel(
    const float* __restrict__ bnd, const float* __restrict__ trans,
    const float* __restrict__ feats,
    const float* __restrict__ pc, const float* __restrict__ pe,
    const int* __restrict__ pb,
    float* __restrict__ dout, int* __restrict__ bestp)
{
    __shared__ float trL[NTAG * 65];
    __shared__ __align__(16) float fv[2][NTAG];
    const int tid = threadIdx.x;
    float c = pc[tid], e = pe[tid];
    int b = pb[tid];
#pragma unroll
    for (int o = 1; o < 64; o <<= 1) {
        c += __shfl_xor(c, o);
        e += __shfl_xor(e, o);
        b |= __shfl_xor(b, o);
    }
    if (!(e <= 1.0e4f)) b = 1;                     // score-error bound
    const float shift = -c;
    float v = (bnd[(size_t)KCH * NTAG + tid] - shift) + trans[STOP_TAG * NTAG + tid];
    int bi = tid;
#pragma unroll
    for (int o = 1; o < 64; o <<= 1) {
        float vo = __shfl_xor(v, o);
        int io = __shfl_xor(bi, o);
        if (vo > v || (vo == v && io < bi)) { v = vo; bi = io; }
    }
    if (tid == 0) { dout[0] = v; dout[T_LEN] = (float)bi; *bestp = bi; }

    if (b) {  // exact sequential score recompute (wave-uniform b)
        load_trans_lds(trans, tid, trL);
        fv[0][tid] = (tid == START_TAG) ? 0.0f : NEGV;
        wave_run<0>(0, T_LEN, feats, trans, nullptr, fv, trL, tid);
        float v2 = fv[0][tid] + trans[STOP_TAG * NTAG + tid];
        int b2 = tid;
#pragma unroll
        for (int o = 1; o < 64; o <<= 1) {
            float vo = __shfl_xor(v2, o);
            int io = __shfl_xor(b2, o);
            if (vo > v2 || (vo == v2 && io < b2)) { v2 = vo; b2 = io; }
        }
        if (tid == 0) { dout[0] = v2; dout[T_LEN] = (float)b2; *bestp = b2; }
    }
}

// ---- emit2: fused prefix chase + packed-uint chase + path writes ----
__global__ __launch_bounds__(64) void emit2_kernel(
    const unsigned char* __restrict__ maps, const unsigned char* __restrict__ smaps,
    const int* __restrict__ bestp, const unsigned int* __restrict__ bpg,
    float* __restrict__ dout)
{
    const int lane = threadIdx.x, k = blockIdx.x;
    const int j = k >> 6;                          // supergroup (SG = 64)
    // prefix chase: smaps hops above supergroup j, then maps down to k+1.
    // All load addresses are static -> prefetchable; only shfls serialize.
    int e = *bestp;
#pragma unroll 1
    for (int jj = NSG - 1; jj > j; --jj) {
        int m = smaps[jj * NTAG + lane];
        e = __shfl(m, e);
    }
#pragma unroll 4
    for (int i = (j + 1) * SG - 1; i > k; --i) {
        int m = maps[(size_t)i * NTAG + lane];
        e = __shfl(m, e);
    }
    const int eblk = e;
    int cur = lane;
    const int t0 = k * CL;
    const size_t base = ((size_t)t0 >> 2) * NTAG + lane;
#pragma unroll 4
    for (int t4 = CL / 4 - 1; t4 >= 0; --t4) {
        unsigned int b4 = bpg[base + (size_t)t4 * NTAG];
#pragma unroll
        for (int jj = 3; jj >= 0; --jj) {
            unsigned int u = __shfl(b4, cur);
            cur = (u >> (8 * jj)) & 255;
            const int t = t0 + t4 * 4 + jj;
            if (t > 0 && lane == eblk) dout[t] = (float)cur;
        }
    }
}

__global__ void beacon_kernel(float* dout, float wsz) { dout[0] = wsz; }

extern "C" void kernel_launch(void* const* d_in, const int* in_sizes, int n_in,
                              void* d_out, int out_size, void* d_ws, size_t ws_size,
                              hipStream_t stream) {
    const float* feats = (const float*)d_in[0];
    const float* trans = (const float*)d_in[1];
    float* dout = (float*)d_out;
    char* ws = (char*)d_ws;

    size_t off = 0;
    auto alloc = [&](size_t bytes) -> void* {
        void* p = ws + off;
        off = (off + bytes + 255) & ~(size_t)255;
        return p;
    };
    unsigned int* bpg = (unsigned int*)alloc((size_t)(T_LEN / 4) * NTAG * 4); // 33.5 MB
    float* bnd    = (float*)alloc((size_t)(KCH + 1) * NTAG * sizeof(float));
    float* ovl    = (float*)alloc((size_t)KCH * NTAG * sizeof(float));
    unsigned char* maps  = (unsigned char*)alloc((size_t)KCH * NTAG);
    unsigned char* smaps = (unsigned char*)alloc((size_t)NSG * NTAG);
    int*   bestp  = (int*)alloc(sizeof(int));
    float* pc     = (float*)alloc(64 * sizeof(float));
    float* pe     = (float*)alloc(64 * sizeof(float));
    int*   pb     = (int*)alloc(64 * sizeof(int));
    const size_t NEED = off;

    if (ws_size < NEED) {
        beacon_kernel<<<1, 1, 0, stream>>>(dout, (float)ws_size);
        return;
    }

    pass1_kernel<<<KCH / WPB, 256, 0, stream>>>(feats, trans, bpg, ovl, bnd, maps);
    mid_kernel<<<NSG + 64, 1024, 0, stream>>>(maps, smaps, bnd, ovl, pc, pe, pb);
    finalize_final_kernel<<<1, 64, 0, stream>>>(bnd, trans, feats, pc, pe, pb, dout, bestp);
    emit2_kernel<<<KCH, 64, 0, stream>>>(maps, smaps, bestp, bpg, dout);
}

// Round 6
// 382.665 us; speedup vs baseline: 1.0474x; 1.0474x over previous
//
#include <hip/hip_runtime.h>
#include <hip/hip_bf16.h>

#define T_LEN 524288
#define NTAG 64
#define START_TAG 62
#define STOP_TAG 63
#define NEGV -10000.0f

// speculative-chunk decomposition, wave-synchronous engine.
// R6: fix the register-allocation occupancy TARGET, not the cap. R3/R4/R5 all
// clamped to VGPR_Count=64 because LDS/block (18.9KB) let the compiler model
// 8 blocks/CU -> 8 waves/SIMD -> 64-reg target; launch_bounds only caps.
// Widening trL stride 65->141 floats inflates LDS to 38.1KB/block -> model
// says 4 blocks/CU -> 4 waves/SIMD -> 128-reg budget, matching the REAL grid
// (1024 blocks = 4/CU). (141 mod 32 = 13, odd -> per-lane reads still 2-way.)
#define KCH 4096         // chunks (= waves)
#define CL  128          // trusted steps per chunk
#define WU  64           // warmup steps (decision collapse; score drift checked)
#define WPB 4            // waves (chunks) per block
#define TRS 141          // trL row stride (floats): odd -> 2-way banks; sizes LDS

#define SG  64           // chunks per supergroup
#define NSG (KCH / SG)   // 64

typedef float v2f __attribute__((ext_vector_type(2)));

struct BlockLDS {
    float trL[NTAG * TRS];                  // 36096 B, shared by 4 waves
    __align__(16) float fv[WPB][2][NTAG];   // 2048 B   -> total 38144 B
};

static __device__ __forceinline__ float max3f(float a, float b, float c) {
    return fmaxf(fmaxf(a, b), c);      // clang fuses to v_max3_f32
}
static __device__ __forceinline__ v2f mk2(float a, float b) {
    v2f r; r.x = a; r.y = b; return r;
}

union Q4 { float4 q; v2f h[2]; };

// Wave-synchronous max-plus engine, register-tr tournament edition.
// Phase A: fv broadcast (uniform ds_read_b128) + tr in VGPRs -> 32 packed
// adds + max3 tree -> gm[8], global max t.
// Phase B (MODE 1): argmax by exact fp equality (fmax returns an input
// bit-exactly; adds recomputed with identical IEEE adds). First-match scan
// = jnp.argmax first-occurrence semantics. fv group via per-lane b128,
// tr group via stride-TRS trL scalar reads (runtime g -> LDS, 2-way banks).
template<int MODE>
__device__ __forceinline__ void wave_run(
    int t0, int nsteps, const float* __restrict__ feats,
    const float* __restrict__ trans,
    unsigned int* __restrict__ bpg, float (*fv)[NTAG],
    const float* __restrict__ trL, int lane)
{
    // ---- transition row in registers, pinned against remat ----
    v2f tr[32];
    {
        const float4* t4 = (const float4*)(trans + (size_t)lane * NTAG);
#pragma unroll
        for (int j = 0; j < 16; ++j) {
            float4 v = t4[j];
            tr[2 * j + 0] = mk2(v.x, v.y);
            tr[2 * j + 1] = mk2(v.z, v.w);
        }
#pragma unroll
        for (int j = 0; j < 32; ++j)
            asm volatile("" : "+v"(tr[j]));
    }
    const float* trrow = &trL[lane * TRS];
    const float* fp = feats + (size_t)t0 * NTAG + lane;
    float fA[4], fB[4];
#pragma unroll
    for (int i = 0; i < 4; ++i) fA[i] = fp[i * NTAG];
    fp += 4 * NTAG;
    unsigned int acc = 0;
    unsigned int* bp = bpg + ((size_t)t0 >> 2) * NTAG + lane;
#pragma unroll 1
    for (int tt = 0; tt < nsteps; tt += 4) {
        const bool hav = (tt + 4 < nsteps);
        if (hav) {
#pragma unroll
            for (int i = 0; i < 4; ++i) fB[i] = fp[i * NTAG];
            fp += 4 * NTAG;
        }
#pragma unroll
        for (int s = 0; s < 4; ++s) {
            const int st = tt + s;
            const float* fvp = fv[st & 1];
            float* fvn = fv[(st + 1) & 1];
            const Q4* fq = (const Q4*)fvp;

            // ---- phase A ----
            float gm[8];
#pragma unroll
            for (int g = 0; g < 8; ++g) {
                Q4 x0 = fq[2 * g + 0];             // uniform -> broadcast
                Q4 x1 = fq[2 * g + 1];
                v2f c01 = x0.h[0] + tr[4 * g + 0];
                v2f c23 = x0.h[1] + tr[4 * g + 1];
                v2f c45 = x1.h[0] + tr[4 * g + 2];
                v2f c67 = x1.h[1] + tr[4 * g + 3];
                const float m1 = max3f(c01.x, c01.y, c23.x);
                const float m2 = max3f(c23.y, c45.x, c45.y);
                const float m3 = max3f(c67.x, c67.y, m1);
                gm[g] = fmaxf(m2, m3);
            }
            const float ga = max3f(gm[0], gm[1], gm[2]);
            const float gb = max3f(gm[3], gm[4], gm[5]);
            const float gc = max3f(gm[6], gm[7], ga);
            const float t  = fmaxf(gb, gc);
            fvn[lane] = t + fA[s];

            if (MODE == 1) {
                // ---- phase B: exact-equality argmax recovery ----
                int g = 7;
                if (gm[6] == t) g = 6;
                if (gm[5] == t) g = 5;
                if (gm[4] == t) g = 4;
                if (gm[3] == t) g = 3;
                if (gm[2] == t) g = 2;
                if (gm[1] == t) g = 1;
                if (gm[0] == t) g = 0;
                const Q4* yq = (const Q4*)(fvp + (g << 3));  // 32B aligned
                Q4 y0 = yq[0];
                Q4 y1 = yq[1];
                const float* tb = trrow + (g << 3);
                const float e0 = y0.h[0].x + tb[0], e1 = y0.h[0].y + tb[1];
                const float e2 = y0.h[1].x + tb[2], e3 = y0.h[1].y + tb[3];
                const float e4 = y1.h[0].x + tb[4], e5 = y1.h[0].y + tb[5];
                const float e6 = y1.h[1].x + tb[6], e7 = y1.h[1].y + tb[7];
                int j = 7;
                if (e6 == t) j = 6;
                if (e5 == t) j = 5;
                if (e4 == t) j = 4;
                if (e3 == t) j = 3;
                if (e2 == t) j = 2;
                if (e1 == t) j = 1;
                if (e0 == t) j = 0;
                const int idx = (g << 3) | j;
                acc |= (unsigned int)idx << (8 * s);
                if (s == 3) {
                    *bp = acc;
                    bp += NTAG;
                    acc = 0;
                }
            }
        }
        if (hav) {
#pragma unroll
            for (int i = 0; i < 4; ++i) fA[i] = fB[i];
        }
    }
}

__device__ __forceinline__ void load_trans_lds(const float* __restrict__ trans,
                                               int lane, float* trL)
{
    const float4* trow = (const float4*)(trans + (size_t)lane * NTAG);
    float* dst = trL + lane * TRS;
#pragma unroll
    for (int j = 0; j < 16; ++j) {
        float4 v = trow[j];
        dst[j * 4 + 0] = v.x; dst[j * 4 + 1] = v.y;
        dst[j * 4 + 2] = v.z; dst[j * 4 + 3] = v.w;
    }
}

// ---- pass1: warmup + trusted chunk + fused backtrack map (bpg re-read) ----
// LDS 38.1KB/block -> compiler occupancy model = 4 blocks/CU = 4 waves/SIMD
// -> 128-VGPR budget; grid 1024 = 4 blocks/CU real. tr[32] stays resident.
__global__ __launch_bounds__(256, 4) void pass1_kernel(
    const float* __restrict__ feats, const float* __restrict__ trans,
    unsigned int* __restrict__ bpg, float* __restrict__ ovl,
    float* __restrict__ bnd, unsigned char* __restrict__ maps)
{
    __shared__ BlockLDS L;
    const int lane = threadIdx.x & 63;
    const int w = threadIdx.x >> 6;
    const int k = blockIdx.x * WPB + w;
    load_trans_lds(trans, lane, L.trL);   // each lane writes & reads its own row

    float (*fv)[NTAG] = L.fv[w];
    if (k == 0) {
        fv[0][lane] = (lane == START_TAG) ? 0.0f : NEGV;
    } else {
        fv[0][lane] = 0.0f;
    }
    if (k > 0) {
        wave_run<0>(k * CL - WU, WU, feats, trans, nullptr, fv, L.trL, lane); // WU even -> fv[0]
        ovl[(size_t)k * NTAG + lane] = fv[0][lane];
    }
    wave_run<1>(k * CL, CL, feats, trans, bpg, fv, L.trL, lane);
    bnd[(size_t)(k + 1) * NTAG + lane] = fv[0][lane];                  // CL even

    // fused backtrack: chase this chunk's bptr (descending t) -> block map.
    // Reads back the bpg words this lane just wrote (same address, L2-hot).
    asm volatile("s_waitcnt vmcnt(0)" ::: "memory");
    int cur = lane;
    const size_t base = ((size_t)(k * CL) >> 2) * NTAG + lane;
#pragma unroll 4
    for (int t4 = CL / 4 - 1; t4 >= 0; --t4) {
        unsigned int b4 = bpg[base + (size_t)t4 * NTAG];
#pragma unroll
        for (int j = 3; j >= 0; --j) {
            unsigned int u = __shfl(b4, cur);
            cur = (u >> (8 * j)) & 255;
        }
    }
    maps[(size_t)k * NTAG + lane] = (unsigned char)cur;
}

// ---- mid: compose (blocks 0..NSG-1) || finalize partial reduce (blocks NSG..NSG+63) ----
__global__ __launch_bounds__(1024) void mid_kernel(
    const unsigned char* __restrict__ maps, unsigned char* __restrict__ smaps,
    const float* __restrict__ bnd, const float* __restrict__ ovl,
    float* __restrict__ pc, float* __restrict__ pe, int* __restrict__ pb)
{
    __shared__ float sc[16], se[16];
    __shared__ int sb[16];
    if (blockIdx.x < NSG) {
        if (threadIdx.x < 64) {            // single-wave map composition
            const int lane = threadIdx.x, j = blockIdx.x;
            int cur = lane;
#pragma unroll 4
            for (int i = (j + 1) * SG - 1; i >= j * SG; --i) {
                int m = maps[(size_t)i * NTAG + lane];
                cur = __shfl(m, cur);
            }
            smaps[j * NTAG + lane] = (unsigned char)cur;
        }
        return;
    }
    const int tid = threadIdx.x, w = tid >> 6, lane = tid & 63;
    const int gw = (blockIdx.x - NSG) * 16 + w;    // 1024 warps total
    float csum = 0.f, esum = 0.f;
    int bad = 0;
    for (int k = 1 + gw; k < KCH; k += 1024) {
        float d = bnd[(size_t)k * NTAG + lane] - ovl[(size_t)k * NTAG + lane];
        float d0 = __shfl(d, 0);
        float sp = fabsf(d - d0);
#pragma unroll
        for (int o = 1; o < 64; o <<= 1) sp = fmaxf(sp, __shfl_xor(sp, o));
        csum += d0; esum += sp;
        if (!(fabsf(d0) < 1.0e7f)) bad = 1;        // incl. NaN
    }
    if (lane == 0) { sc[w] = csum; se[w] = esum; sb[w] = bad; }
    __syncthreads();
    if (tid == 0) {
        float c = 0.f, e = 0.f; int b = 0;
        for (int i = 0; i < 16; ++i) { c += sc[i]; e += se[i]; b |= sb[i]; }
        pc[blockIdx.x - NSG] = c; pe[blockIdx.x - NSG] = e; pb[blockIdx.x - NSG] = b;
    }
}

// ---- finalize: combine partials + terminal argmax + integrated fallback ----
__global__ __launch_bounds__(64) void finalize_final_kernel(
    const float* __restrict__ bnd, const float* __restrict__ trans,
    const float* __restrict__ feats,
    const float* __restrict__ pc, const float* __restrict__ pe,
    const int* __restrict__ pb,
    float* __restrict__ dout, int* __restrict__ bestp)
{
    __shared__ float trL[NTAG * TRS];
    __shared__ __align__(16) float fv[2][NTAG];
    const int tid = threadIdx.x;
    float c = pc[tid], e = pe[tid];
    int b = pb[tid];
#pragma unroll
    for (int o = 1; o < 64; o <<= 1) {
        c += __shfl_xor(c, o);
        e += __shfl_xor(e, o);
        b |= __shfl_xor(b, o);
    }
    if (!(e <= 1.0e4f)) b = 1;                     // score-error bound
    const float shift = -c;
    float v = (bnd[(size_t)KCH * NTAG + tid] - shift) + trans[STOP_TAG * NTAG + tid];
    int bi = tid;
#pragma unroll
    for (int o = 1; o < 64; o <<= 1) {
        float vo = __shfl_xor(v, o);
        int io = __shfl_xor(bi, o);
        if (vo > v || (vo == v && io < bi)) { v = vo; bi = io; }
    }
    if (tid == 0) { dout[0] = v; dout[T_LEN] = (float)bi; *bestp = bi; }

    if (b) {  // exact sequential score recompute (wave-uniform b)
        load_trans_lds(trans, tid, trL);
        fv[0][tid] = (tid == START_TAG) ? 0.0f : NEGV;
        wave_run<0>(0, T_LEN, feats, trans, nullptr, fv, trL, tid);
        float v2 = fv[0][tid] + trans[STOP_TAG * NTAG + tid];
        int b2 = tid;
#pragma unroll
        for (int o = 1; o < 64; o <<= 1) {
            float vo = __shfl_xor(v2, o);
            int io = __shfl_xor(b2, o);
            if (vo > v2 || (vo == v2 && io < b2)) { v2 = vo; b2 = io; }
        }
        if (tid == 0) { dout[0] = v2; dout[T_LEN] = (float)b2; *bestp = b2; }
    }
}

// ---- emit2: fused prefix chase + packed-uint chase + path writes ----
__global__ __launch_bounds__(64) void emit2_kernel(
    const unsigned char* __restrict__ maps, const unsigned char* __restrict__ smaps,
    const int* __restrict__ bestp, const unsigned int* __restrict__ bpg,
    float* __restrict__ dout)
{
    const int lane = threadIdx.x, k = blockIdx.x;
    const int j = k >> 6;                          // supergroup (SG = 64)
    // prefix chase: smaps hops above supergroup j, then maps down to k+1.
    // All load addresses are static -> prefetchable; only shfls serialize.
    int e = *bestp;
#pragma unroll 4
    for (int jj = NSG - 1; jj > j; --jj) {
        int m = smaps[jj * NTAG + lane];
        e = __shfl(m, e);
    }
#pragma unroll 4
    for (int i = (j + 1) * SG - 1; i > k; --i) {
        int m = maps[(size_t)i * NTAG + lane];
        e = __shfl(m, e);
    }
    const int eblk = e;
    int cur = lane;
    const int t0 = k * CL;
    const size_t base = ((size_t)t0 >> 2) * NTAG + lane;
#pragma unroll 4
    for (int t4 = CL / 4 - 1; t4 >= 0; --t4) {
        unsigned int b4 = bpg[base + (size_t)t4 * NTAG];
#pragma unroll
        for (int jj = 3; jj >= 0; --jj) {
            unsigned int u = __shfl(b4, cur);
            cur = (u >> (8 * jj)) & 255;
            const int t = t0 + t4 * 4 + jj;
            if (t > 0 && lane == eblk) dout[t] = (float)cur;
        }
    }
}

__global__ void beacon_kernel(float* dout, float wsz) { dout[0] = wsz; }

extern "C" void kernel_launch(void* const* d_in, const int* in_sizes, int n_in,
                              void* d_out, int out_size, void* d_ws, size_t ws_size,
                              hipStream_t stream) {
    const float* feats = (const float*)d_in[0];
    const float* trans = (const float*)d_in[1];
    float* dout = (float*)d_out;
    char* ws = (char*)d_ws;

    size_t off = 0;
    auto alloc = [&](size_t bytes) -> void* {
        void* p = ws + off;
        off = (off + bytes + 255) & ~(size_t)255;
        return p;
    };
    unsigned int* bpg = (unsigned int*)alloc((size_t)(T_LEN / 4) * NTAG * 4); // 33.5 MB
    float* bnd    = (float*)alloc((size_t)(KCH + 1) * NTAG * sizeof(float));
    float* ovl    = (float*)alloc((size_t)KCH * NTAG * sizeof(float));
    unsigned char* maps  = (unsigned char*)alloc((size_t)KCH * NTAG);
    unsigned char* smaps = (unsigned char*)alloc((size_t)NSG * NTAG);
    int*   bestp  = (int*)alloc(sizeof(int));
    float* pc     = (float*)alloc(64 * sizeof(float));
    float* pe     = (float*)alloc(64 * sizeof(float));
    int*   pb     = (int*)alloc(64 * sizeof(int));
    const size_t NEED = off;

    if (ws_size < NEED) {
        beacon_kernel<<<1, 1, 0, stream>>>(dout, (float)ws_size);
        return;
    }

    pass1_kernel<<<KCH / WPB, 256, 0, stream>>>(feats, trans, bpg, ovl, bnd, maps);
    mid_kernel<<<NSG + 64, 1024, 0, stream>>>(maps, smaps, bnd, ovl, pc, pe, pb);
    finalize_final_kernel<<<1, 64, 0, stream>>>(bnd, trans, feats, pc, pe, pb, dout, bestp);
    emit2_kernel<<<KCH, 64, 0, stream>>>(maps, smaps, bestp, bpg, dout);
}

// Round 7
// 381.921 us; speedup vs baseline: 1.0494x; 1.0019x over previous
//
#include <hip/hip_runtime.h>
#include <hip/hip_bf16.h>

#define T_LEN 524288
#define NTAG 64
#define START_TAG 62
#define STOP_TAG 63
#define NEGV -10000.0f

// speculative-chunk decomposition, wave-synchronous engine.
// R7: the allocator clamped VGPR_Count=64 in R3-R6 because the backend
// schedules for MAX occupancy (8 waves/EU -> 64-reg target); launch_bounds'
// 2nd arg only sets the MINimum waves-per-eu, and asm pins don't force
// cross-loop liveness. amdgpu_waves_per_eu(4,4) sets the MAXIMUM too ->
// 128-reg pressure target -> tr[32] (64 regs) can stay arch-resident.
// Pins moved inside the K-loop so spilling between iterations never pays.
#define KCH 4096         // chunks (= waves)
#define CL  128          // trusted steps per chunk
#define WU  64           // warmup steps (decision collapse; score drift checked)
#define WPB 4            // waves (chunks) per block
#define TRS 141          // trL row stride (floats): odd -> 2-way banks

#define SG  64           // chunks per supergroup
#define NSG (KCH / SG)   // 64

typedef float v2f __attribute__((ext_vector_type(2)));

struct BlockLDS {
    float trL[NTAG * TRS];                  // 36096 B, shared by 4 waves
    __align__(16) float fv[WPB][2][NTAG];   // 2048 B   -> total 38144 B
};

static __device__ __forceinline__ float max3f(float a, float b, float c) {
    return fmaxf(fmaxf(a, b), c);      // clang fuses to v_max3_f32
}
static __device__ __forceinline__ v2f mk2(float a, float b) {
    v2f r; r.x = a; r.y = b; return r;
}

union Q4 { float4 q; v2f h[2]; };

// Wave-synchronous max-plus engine, register-tr tournament edition.
// Phase A: fv broadcast (uniform ds_read_b128) + tr in VGPRs -> 32 packed
// adds + max3 tree -> gm[8], global max t.
// Phase B (MODE 1): argmax by exact fp equality (fmax returns an input
// bit-exactly; adds recomputed with identical IEEE adds). First-match scan
// = jnp.argmax first-occurrence semantics. fv group via per-lane b128,
// tr group via stride-TRS trL scalar reads (runtime g -> LDS, 2-way banks).
template<int MODE>
__device__ __forceinline__ void wave_run(
    int t0, int nsteps, const float* __restrict__ feats,
    const float* __restrict__ trans,
    unsigned int* __restrict__ bpg, float (*fv)[NTAG],
    const float* __restrict__ trL, int lane)
{
    // ---- transition row in registers ----
    v2f tr[32];
    {
        const float4* t4 = (const float4*)(trans + (size_t)lane * NTAG);
#pragma unroll
        for (int j = 0; j < 16; ++j) {
            float4 v = t4[j];
            tr[2 * j + 0] = mk2(v.x, v.y);
            tr[2 * j + 1] = mk2(v.z, v.w);
        }
    }
    const float* trrow = &trL[lane * TRS];
    const float* fp = feats + (size_t)t0 * NTAG + lane;
    float fA[4], fB[4];
#pragma unroll
    for (int i = 0; i < 4; ++i) fA[i] = fp[i * NTAG];
    fp += 4 * NTAG;
    unsigned int acc = 0;
    unsigned int* bp = bpg + ((size_t)t0 >> 2) * NTAG + lane;
#pragma unroll 1
    for (int tt = 0; tt < nsteps; tt += 4) {
        // anti-remat pin: tr must be live in arch VGPRs at every iteration
        // boundary -> spilling/reloading between pins is never profitable.
#pragma unroll
        for (int j = 0; j < 32; ++j)
            asm volatile("" : "+v"(tr[j]));
        const bool hav = (tt + 4 < nsteps);
        if (hav) {
#pragma unroll
            for (int i = 0; i < 4; ++i) fB[i] = fp[i * NTAG];
            fp += 4 * NTAG;
        }
#pragma unroll
        for (int s = 0; s < 4; ++s) {
            const int st = tt + s;
            const float* fvp = fv[st & 1];
            float* fvn = fv[(st + 1) & 1];
            const Q4* fq = (const Q4*)fvp;

            // ---- phase A ----
            float gm[8];
#pragma unroll
            for (int g = 0; g < 8; ++g) {
                Q4 x0 = fq[2 * g + 0];             // uniform -> broadcast
                Q4 x1 = fq[2 * g + 1];
                v2f c01 = x0.h[0] + tr[4 * g + 0];
                v2f c23 = x0.h[1] + tr[4 * g + 1];
                v2f c45 = x1.h[0] + tr[4 * g + 2];
                v2f c67 = x1.h[1] + tr[4 * g + 3];
                const float m1 = max3f(c01.x, c01.y, c23.x);
                const float m2 = max3f(c23.y, c45.x, c45.y);
                const float m3 = max3f(c67.x, c67.y, m1);
                gm[g] = fmaxf(m2, m3);
            }
            const float ga = max3f(gm[0], gm[1], gm[2]);
            const float gb = max3f(gm[3], gm[4], gm[5]);
            const float gc = max3f(gm[6], gm[7], ga);
            const float t  = fmaxf(gb, gc);
            fvn[lane] = t + fA[s];

            if (MODE == 1) {
                // ---- phase B: exact-equality argmax recovery ----
                int g = 7;
                if (gm[6] == t) g = 6;
                if (gm[5] == t) g = 5;
                if (gm[4] == t) g = 4;
                if (gm[3] == t) g = 3;
                if (gm[2] == t) g = 2;
                if (gm[1] == t) g = 1;
                if (gm[0] == t) g = 0;
                const Q4* yq = (const Q4*)(fvp + (g << 3));  // 32B aligned
                Q4 y0 = yq[0];
                Q4 y1 = yq[1];
                const float* tb = trrow + (g << 3);
                const float e0 = y0.h[0].x + tb[0], e1 = y0.h[0].y + tb[1];
                const float e2 = y0.h[1].x + tb[2], e3 = y0.h[1].y + tb[3];
                const float e4 = y1.h[0].x + tb[4], e5 = y1.h[0].y + tb[5];
                const float e6 = y1.h[1].x + tb[6], e7 = y1.h[1].y + tb[7];
                int j = 7;
                if (e6 == t) j = 6;
                if (e5 == t) j = 5;
                if (e4 == t) j = 4;
                if (e3 == t) j = 3;
                if (e2 == t) j = 2;
                if (e1 == t) j = 1;
                if (e0 == t) j = 0;
                const int idx = (g << 3) | j;
                acc |= (unsigned int)idx << (8 * s);
                if (s == 3) {
                    *bp = acc;
                    bp += NTAG;
                    acc = 0;
                }
            }
        }
        if (hav) {
#pragma unroll
            for (int i = 0; i < 4; ++i) fA[i] = fB[i];
        }
    }
}

__device__ __forceinline__ void load_trans_lds(const float* __restrict__ trans,
                                               int lane, float* trL)
{
    const float4* trow = (const float4*)(trans + (size_t)lane * NTAG);
    float* dst = trL + lane * TRS;
#pragma unroll
    for (int j = 0; j < 16; ++j) {
        float4 v = trow[j];
        dst[j * 4 + 0] = v.x; dst[j * 4 + 1] = v.y;
        dst[j * 4 + 2] = v.z; dst[j * 4 + 3] = v.w;
    }
}

// ---- pass1: warmup + trusted chunk + fused backtrack map (bpg re-read) ----
// amdgpu_waves_per_eu(4,4): occupancy max = 4 waves/EU -> 128-VGPR pressure
// target (8-wave/64-reg scheduling is what clamped R3-R6). Grid 1024 blocks
// = 4 blocks/CU real, matching the model.
__global__ __attribute__((amdgpu_flat_work_group_size(256, 256),
                          amdgpu_waves_per_eu(4, 4)))
void pass1_kernel(
    const float* __restrict__ feats, const float* __restrict__ trans,
    unsigned int* __restrict__ bpg, float* __restrict__ ovl,
    float* __restrict__ bnd, unsigned char* __restrict__ maps)
{
    __shared__ BlockLDS L;
    const int lane = threadIdx.x & 63;
    const int w = threadIdx.x >> 6;
    const int k = blockIdx.x * WPB + w;
    load_trans_lds(trans, lane, L.trL);   // each lane writes & reads its own row

    float (*fv)[NTAG] = L.fv[w];
    if (k == 0) {
        fv[0][lane] = (lane == START_TAG) ? 0.0f : NEGV;
    } else {
        fv[0][lane] = 0.0f;
    }
    if (k > 0) {
        wave_run<0>(k * CL - WU, WU, feats, trans, nullptr, fv, L.trL, lane); // WU even -> fv[0]
        ovl[(size_t)k * NTAG + lane] = fv[0][lane];
    }
    wave_run<1>(k * CL, CL, feats, trans, bpg, fv, L.trL, lane);
    bnd[(size_t)(k + 1) * NTAG + lane] = fv[0][lane];                  // CL even

    // fused backtrack: chase this chunk's bptr (descending t) -> block map.
    // Reads back the bpg words this lane just wrote (same address, L2-hot).
    asm volatile("s_waitcnt vmcnt(0)" ::: "memory");
    int cur = lane;
    const size_t base = ((size_t)(k * CL) >> 2) * NTAG + lane;
#pragma unroll 4
    for (int t4 = CL / 4 - 1; t4 >= 0; --t4) {
        unsigned int b4 = bpg[base + (size_t)t4 * NTAG];
#pragma unroll
        for (int j = 3; j >= 0; --j) {
            unsigned int u = __shfl(b4, cur);
            cur = (u >> (8 * j)) & 255;
        }
    }
    maps[(size_t)k * NTAG + lane] = (unsigned char)cur;
}

// ---- mid: compose (blocks 0..NSG-1) || finalize partial reduce (blocks NSG..NSG+63) ----
__global__ __launch_bounds__(1024) void mid_kernel(
    const unsigned char* __restrict__ maps, unsigned char* __restrict__ smaps,
    const float* __restrict__ bnd, const float* __restrict__ ovl,
    float* __restrict__ pc, float* __restrict__ pe, int* __restrict__ pb)
{
    __shared__ float sc[16], se[16];
    __shared__ int sb[16];
    if (blockIdx.x < NSG) {
        if (threadIdx.x < 64) {            // single-wave map composition
            const int lane = threadIdx.x, j = blockIdx.x;
            int cur = lane;
#pragma unroll 4
            for (int i = (j + 1) * SG - 1; i >= j * SG; --i) {
                int m = maps[(size_t)i * NTAG + lane];
                cur = __shfl(m, cur);
            }
            smaps[j * NTAG + lane] = (unsigned char)cur;
        }
        return;
    }
    const int tid = threadIdx.x, w = tid >> 6, lane = tid & 63;
    const int gw = (blockIdx.x - NSG) * 16 + w;    // 1024 warps total
    float csum = 0.f, esum = 0.f;
    int bad = 0;
    for (int k = 1 + gw; k < KCH; k += 1024) {
        float d = bnd[(size_t)k * NTAG + lane] - ovl[(size_t)k * NTAG + lane];
        float d0 = __shfl(d, 0);
        float sp = fabsf(d - d0);
#pragma unroll
        for (int o = 1; o < 64; o <<= 1) sp = fmaxf(sp, __shfl_xor(sp, o));
        csum += d0; esum += sp;
        if (!(fabsf(d0) < 1.0e7f)) bad = 1;        // incl. NaN
    }
    if (lane == 0) { sc[w] = csum; se[w] = esum; sb[w] = bad; }
    __syncthreads();
    if (tid == 0) {
        float c = 0.f, e = 0.f; int b = 0;
        for (int i = 0; i < 16; ++i) { c += sc[i]; e += se[i]; b |= sb[i]; }
        pc[blockIdx.x - NSG] = c; pe[blockIdx.x - NSG] = e; pb[blockIdx.x - NSG] = b;
    }
}

// ---- finalize: combine partials + terminal argmax + integrated fallback ----
__global__ __launch_bounds__(64) void finalize_final_kernel(
    const float* __restrict__ bnd, const float* __restrict__ trans,
    const float* __restrict__ feats,
    const float* __restrict__ pc, const float* __restrict__ pe,
    const int* __restrict__ pb,
    float* __restrict__ dout, int* __restrict__ bestp)
{
    __shared__ float trL[NTAG * TRS];
    __shared__ __align__(16) float fv[2][NTAG];
    const int tid = threadIdx.x;
    float c = pc[tid], e = pe[tid];
    int b = pb[tid];
#pragma unroll
    for (int o = 1; o < 64; o <<= 1) {
        c += __shfl_xor(c, o);
        e += __shfl_xor(e, o);
        b |= __shfl_xor(b, o);
    }
    if (!(e <= 1.0e4f)) b = 1;                     // score-error bound
    const float shift = -c;
    float v = (bnd[(size_t)KCH * NTAG + tid] - shift) + trans[STOP_TAG * NTAG + tid];
    int bi = tid;
#pragma unroll
    for (int o = 1; o < 64; o <<= 1) {
        float vo = __shfl_xor(v, o);
        int io = __shfl_xor(bi, o);
        if (vo > v || (vo == v && io < bi)) { v = vo; bi = io; }
    }
    if (tid == 0) { dout[0] = v; dout[T_LEN] = (float)bi; *bestp = bi; }

    if (b) {  // exact sequential score recompute (wave-uniform b)
        load_trans_lds(trans, tid, trL);
        fv[0][tid] = (tid == START_TAG) ? 0.0f : NEGV;
        wave_run<0>(0, T_LEN, feats, trans, nullptr, fv, trL, tid);
        float v2 = fv[0][tid] + trans[STOP_TAG * NTAG + tid];
        int b2 = tid;
#pragma unroll
        for (int o = 1; o < 64; o <<= 1) {
            float vo = __shfl_xor(v2, o);
            int io = __shfl_xor(b2, o);
            if (vo > v2 || (vo == v2 && io < b2)) { v2 = vo; b2 = io; }
        }
        if (tid == 0) { dout[0] = v2; dout[T_LEN] = (float)b2; *bestp = b2; }
    }
}

// ---- emit2: fused prefix chase + packed-uint chase + path writes ----
__global__ __launch_bounds__(64) void emit2_kernel(
    const unsigned char* __restrict__ maps, const unsigned char* __restrict__ smaps,
    const int* __restrict__ bestp, const unsigned int* __restrict__ bpg,
    float* __restrict__ dout)
{
    const int lane = threadIdx.x, k = blockIdx.x;
    const int j = k >> 6;                          // supergroup (SG = 64)
    // prefix chase: smaps hops above supergroup j, then maps down to k+1.
    // All load addresses are static -> prefetchable; only shfls serialize.
    int e = *bestp;
#pragma unroll 4
    for (int jj = NSG - 1; jj > j; --jj) {
        int m = smaps[jj * NTAG + lane];
        e = __shfl(m, e);
    }
#pragma unroll 4
    for (int i = (j + 1) * SG - 1; i > k; --i) {
        int m = maps[(size_t)i * NTAG + lane];
        e = __shfl(m, e);
    }
    const int eblk = e;
    int cur = lane;
    const int t0 = k * CL;
    const size_t base = ((size_t)t0 >> 2) * NTAG + lane;
#pragma unroll 4
    for (int t4 = CL / 4 - 1; t4 >= 0; --t4) {
        unsigned int b4 = bpg[base + (size_t)t4 * NTAG];
#pragma unroll
        for (int jj = 3; jj >= 0; --jj) {
            unsigned int u = __shfl(b4, cur);
            cur = (u >> (8 * jj)) & 255;
            const int t = t0 + t4 * 4 + jj;
            if (t > 0 && lane == eblk) dout[t] = (float)cur;
        }
    }
}

__global__ void beacon_kernel(float* dout, float wsz) { dout[0] = wsz; }

extern "C" void kernel_launch(void* const* d_in, const int* in_sizes, int n_in,
                              void* d_out, int out_size, void* d_ws, size_t ws_size,
                              hipStream_t stream) {
    const float* feats = (const float*)d_in[0];
    const float* trans = (const float*)d_in[1];
    float* dout = (float*)d_out;
    char* ws = (char*)d_ws;

    size_t off = 0;
    auto alloc = [&](size_t bytes) -> void* {
        void* p = ws + off;
        off = (off + bytes + 255) & ~(size_t)255;
        return p;
    };
    unsigned int* bpg = (unsigned int*)alloc((size_t)(T_LEN / 4) * NTAG * 4); // 33.5 MB
    float* bnd    = (float*)alloc((size_t)(KCH + 1) * NTAG * sizeof(float));
    float* ovl    = (float*)alloc((size_t)KCH * NTAG * sizeof(float));
    unsigned char* maps  = (unsigned char*)alloc((size_t)KCH * NTAG);
    unsigned char* smaps = (unsigned char*)alloc((size_t)NSG * NTAG);
    int*   bestp  = (int*)alloc(sizeof(int));
    float* pc     = (float*)alloc(64 * sizeof(float));
    float* pe     = (float*)alloc(64 * sizeof(float));
    int*   pb     = (int*)alloc(64 * sizeof(int));
    const size_t NEED = off;

    if (ws_size < NEED) {
        beacon_kernel<<<1, 1, 0, stream>>>(dout, (float)ws_size);
        return;
    }

    pass1_kernel<<<KCH / WPB, 256, 0, stream>>>(feats, trans, bpg, ovl, bnd, maps);
    mid_kernel<<<NSG + 64, 1024, 0, stream>>>(maps, smaps, bnd, ovl, pc, pe, pb);
    finalize_final_kernel<<<1, 64, 0, stream>>>(bnd, trans, feats, pc, pe, pb, dout, bestp);
    emit2_kernel<<<KCH, 64, 0, stream>>>(maps, smaps, bestp, bpg, dout);
}